// Round 7
// baseline (644.389 us; speedup 1.0000x reference)
//
#include <hip/hip_runtime.h>
#include <hip/hip_fp16.h>
#include <math.h>

#define N_NODES 100000
#define N_EDGES 3200000
#define F_INF   500
#define H_DIM   16
#define C_DIM   3

// bucket partition parameters
#define NB      782          // buckets of 128 nodes: bucket = dst >> 7
#define CAP     4608         // slots per bucket (mean 4096, sd ~64 -> +8 sigma)
#define GPAD    16           // gcur stride in ints (64B)
#define EPB     16384        // edges per partition block
#define NBLK_PART ((N_EDGES + EPB - 1) / EPB)   // 196

// workspace layout in 4-byte elements
#define OFF_GCUR  0                      // int[NB*GPAD] = 12512
#define OFF_DINV  12512                  // float[100000]
#define OFF_PAIRS 112512                 // uint[NB*CAP] = 3603456 (dst-sorted after k_sort)
#define OFF_ROWS  3715968                // int[NB*128] = 100096, packed (start_in_bucket<<16)|cnt
#define OFF_H1H   3816064                // uint[800000]: fp16 h1s rows (8 uints = 16 half)
#define OFF_H2H   4616064                // uint[200000]: fp16 h2s rows (2 uints = 4 half)

typedef float        f32x4 __attribute__((ext_vector_type(4)));
typedef unsigned int u32x4 __attribute__((ext_vector_type(4)));
typedef unsigned int u32x2 __attribute__((ext_vector_type(2)));

template <typename T>
__device__ inline T ntload(const T* p) { return __builtin_nontemporal_load(p); }
template <typename T>
__device__ inline void ntstore(T* p, T v) { __builtin_nontemporal_store(v, p); }

__device__ inline float2 h2f(unsigned u) {
    __half2 h = *reinterpret_cast<__half2*>(&u);
    return __half22float2(h);
}
__device__ inline unsigned f2h(float a, float b) {
    __half2 h = __floats2half2_rn(a, b);
    return *reinterpret_cast<unsigned*>(&h);
}

// ---------------- init per-bucket cursors ----------------
__global__ void k_init(int* __restrict__ gcur) {
    int b = blockIdx.x * 256 + threadIdx.x;
    if (b < NB) gcur[b * GPAD] = b * CAP;
}

// ---------------- bucket partition with in-LDS sort + coalesced flush ----------------
__global__ __launch_bounds__(512) void k_part(const int* __restrict__ src,
                                              const int* __restrict__ dst,
                                              int* __restrict__ gcur,
                                              unsigned int* __restrict__ pairs) {
    __shared__ unsigned sbuf[EPB];    // 64 KB staging, sorted by bucket
    __shared__ int lcnt[NB];
    __shared__ int lbase[NB];
    __shared__ int lstart[NB];
    __shared__ int lrank[NB];
    __shared__ int wtot[8];
    int t = threadIdx.x;
    int wid = t >> 6, lane = t & 63;
    int e0 = blockIdx.x * EPB;
    for (int i = t; i < NB; i += 512) { lcnt[i] = 0; lrank[i] = 0; }
    __syncthreads();
    // phase 1: histogram
    for (int i = t; i < EPB; i += 512) {
        int e = e0 + i;
        if (e < N_EDGES) atomicAdd(&lcnt[ntload(dst + e) >> 7], 1);
    }
    __syncthreads();
    // phase 2: global reserve
    for (int b = t; b < NB; b += 512) {
        int c = lcnt[b];
        lbase[b] = c ? atomicAdd(&gcur[b * GPAD], c) : 0;
    }
    // phase 2.5: block-local exclusive scan lcnt -> lstart (8 waves x 128 bins)
    {
        int b0 = wid * 128 + lane * 2;
        int c0 = (b0 < NB) ? lcnt[b0] : 0;
        int c1 = (b0 + 1 < NB) ? lcnt[b0 + 1] : 0;
        int s = c0 + c1;
        int inc = s;
        for (int o = 1; o < 64; o <<= 1) { int y = __shfl_up(inc, o); if (lane >= o) inc += y; }
        if (lane == 63) wtot[wid] = inc;
        int excl = inc - s;
        if (b0 < NB) lstart[b0] = excl;
        if (b0 + 1 < NB) lstart[b0 + 1] = excl + c0;
    }
    __syncthreads();
    if (t == 0) { int r = 0; for (int w = 0; w < 8; ++w) { int v = wtot[w]; wtot[w] = r; r += v; } }
    __syncthreads();
    {
        int b0 = wid * 128 + lane * 2;
        int add = wtot[wid];
        if (b0 < NB) lstart[b0] += add;
        if (b0 + 1 < NB) lstart[b0 + 1] += add;
    }
    __syncthreads();
    // phase 3: scatter into LDS staging (sorted by bucket)
    for (int i = t; i < EPB; i += 512) {
        int e = e0 + i;
        if (e < N_EDGES) {
            int d = ntload(dst + e);
            int b = d >> 7;
            int r = atomicAdd(&lrank[b], 1);
            sbuf[lstart[b] + r] = ((unsigned)ntload(src + e) << 7) | (unsigned)(d & 127);
        }
    }
    __syncthreads();
    // phase 4: coalesced flush, one wave per bucket round-robin
    for (int b = wid; b < NB; b += 8) {
        int c = lcnt[b], ls = lstart[b], gb = lbase[b];
        int lim = (b + 1) * CAP;
        for (int i = lane; i < c; i += 64) {
            int pos = gb + i;
            if (pos < lim)   // safety clamp (statistically never hit)
                pairs[pos] = sbuf[ls + i];
        }
    }
}

// ---------------- per-bucket counting sort by local dst -> CSR rows + dinv ----------------
__global__ __launch_bounds__(512) void k_sort(unsigned int* __restrict__ pairs,
                                              const int* __restrict__ gcur,
                                              float* __restrict__ dinv,
                                              int* __restrict__ rows) {
    __shared__ unsigned sbuf[CAP];   // 18 KB in
    __shared__ unsigned sout[CAP];   // 18 KB sorted
    __shared__ int cnt[128];
    __shared__ int start[128];
    __shared__ int rank[128];
    int b = blockIdx.x, t = threadIdx.x;
    if (t < 128) { cnt[t] = 0; rank[t] = 0; }
    __syncthreads();
    int base = b * CAP;
    int n = min(gcur[b * GPAD] - base, CAP);
    for (int i = t; i < n; i += 512) {
        unsigned p = ntload(pairs + base + i);
        sbuf[i] = p;
        atomicAdd(&cnt[p & 127], 1);
    }
    __syncthreads();
    // wave 0: exclusive scan of 128 bins + packed row table
    if (t < 64) {
        int c0 = cnt[2 * t], c1 = cnt[2 * t + 1];
        int s = c0 + c1;
        int inc = s;
        for (int o = 1; o < 64; o <<= 1) { int y = __shfl_up(inc, o); if (t >= o) inc += y; }
        int excl = inc - s;
        start[2 * t] = excl;
        start[2 * t + 1] = excl + c0;
        rows[b * 128 + 2 * t]     = (excl << 16) | c0;
        rows[b * 128 + 2 * t + 1] = ((excl + c0) << 16) | c1;
    }
    // waves 1-2: dinv from histogram (cnt is final after the barrier above)
    if (t >= 64 && t < 192) {
        int l = t - 64;
        int v = b * 128 + l;
        if (v < N_NODES) dinv[v] = rsqrtf((float)(cnt[l] + 1));
    }
    __syncthreads();
    // scatter to sorted LDS, then coalesced flush back to global
    for (int i = t; i < n; i += 512) {
        unsigned p = sbuf[i];
        int k = p & 127;
        int r = atomicAdd(&rank[k], 1);
        sout[start[k] + r] = p;
    }
    __syncthreads();
    for (int i = t; i < n; i += 512) ntstore(pairs + base + i, sout[i]);
}

// ---------------- GEMM1: h1h = fp16(dinv * (X @ W1)) ----------------
// r7: r6 was LDS-BW-bound (W re-read from LDS: 5 B/FMA = 4 GB -> ~51 us floor).
// W must be an SGPR broadcast -> each lane computes ALL 16 cols of one row
// (C=16, R=1). Thread shortage (100K rows = 6 waves/CU) fixed by wave-level
// k-split: 8 waves/block; wave wid: rows (wid>>2)*64+lane, k-slice g=wid&3
// (16 k of each 64-k round; W address wave-uniform -> s_load, 0 LDS traffic).
// 16 fp32 partials/lane, one cross-wave LDS reduce at the end (reuses xs).
// LDS = 0.25 B/FMA (x only); grid 782 x 8 = 24 waves/CU; HBM-bound ~45-55 us.
#define GK_ROWS 128
#define GK_STRIDE 68         // 64 k + 4 pad (stride%32=4 -> even 8-way b128, free)
#define GK_ROUNDS 8          // 7x64 + 52 = 500
__global__ __launch_bounds__(512, 6) void k_gemm1(const float* __restrict__ x,
                                                  const float* __restrict__ W1,
                                                  const float* __restrict__ dinv,
                                                  unsigned int* __restrict__ h1h) {
    __shared__ float smem[GK_ROWS * GK_STRIDE];  // 34.8 KB: xs rounds, then reduce buf
    int t = threadIdx.x;
    int row0 = blockIdx.x * GK_ROWS;
    // staging mapping: 16 lanes per row -> 256 B contiguous per row
    int cc = t & 15;          // 16B chunk (k-offset cc*4 within the 64-k round)
    int rr = t >> 4;          // 0..31
    // compute mapping
    int lane = t & 63;
    int wid  = t >> 6;        // 0..7
    int g    = wid & 3;       // k-slice within the round
    int crow = (wid >> 2) * 64 + lane;   // local row 0..127
    int grow = row0 + crow;
    bool rowok = grow < N_NODES;

    float acc[16];
#pragma unroll
    for (int j = 0; j < 16; ++j) acc[j] = 0.f;

    f32x4 vreg[4];
    // prologue: round 0 loads (kw=64, all 16 chunks valid)
#pragma unroll
    for (int s = 0; s < 4; ++s) {
        int gr = row0 + s * 32 + rr;
        if (gr < N_NODES)
            vreg[s] = ntload(reinterpret_cast<const f32x4*>(x + (size_t)gr * F_INF + cc * 4));
    }

#pragma unroll 1
    for (int rd = 0; rd < GK_ROUNDS; ++rd) {
        int k0 = rd * 64;
        int kw = (rd < GK_ROUNDS - 1) ? 64 : (F_INF - 64 * (GK_ROUNDS - 1));  // 64 / 52
        __syncthreads();      // previous consumers of smem done
        if (cc * 4 < kw) {
#pragma unroll
            for (int s = 0; s < 4; ++s) {
                int r = s * 32 + rr;
                if (row0 + r < N_NODES) {
                    float* p = smem + r * GK_STRIDE + cc * 4;
                    p[0] = vreg[s].x; p[1] = vreg[s].y; p[2] = vreg[s].z; p[3] = vreg[s].w;
                }
            }
        }
        __syncthreads();
        // prefetch next round (HBM latency hides under the FMA phase)
        if (rd < GK_ROUNDS - 1) {
            int nk0 = k0 + 64;
            int nkw = (rd + 1 < GK_ROUNDS - 1) ? 64 : (F_INF - 64 * (GK_ROUNDS - 1));
            if (cc * 4 < nkw) {
#pragma unroll
                for (int s = 0; s < 4; ++s) {
                    int gr = row0 + s * 32 + rr;
                    if (gr < N_NODES)
                        vreg[s] = ntload(reinterpret_cast<const f32x4*>(x + (size_t)gr * F_INF + nk0 + cc * 4));
                }
            }
        }
        // compute: slice g covers k in [k0+g*16, k0+g*16+klen)
        int klen = kw - g * 16; if (klen > 16) klen = 16;  // 16, or 4 (last round, g=3)
        if (klen > 0 && rowok) {
            const float* xr = smem + crow * GK_STRIDE + g * 16;
            const float* Wu = W1 + (k0 + g * 16) * 16;     // wave-uniform -> s_load
            if (klen == 16) {
#pragma unroll
                for (int c4 = 0; c4 < 4; ++c4) {
                    f32x4 xv = *reinterpret_cast<const f32x4*>(xr + c4 * 4);
#pragma unroll
                    for (int kk = 0; kk < 4; ++kk) {
                        float xvk = xv[kk];
                        const float* wk = Wu + (c4 * 4 + kk) * 16;
#pragma unroll
                        for (int j = 0; j < 16; ++j) acc[j] = fmaf(xvk, wk[j], acc[j]);
                    }
                }
            } else {
                f32x4 xv = *reinterpret_cast<const f32x4*>(xr);
#pragma unroll
                for (int kk = 0; kk < 4; ++kk) {
                    float xvk = xv[kk];
                    const float* wk = Wu + kk * 16;
#pragma unroll
                    for (int j = 0; j < 16; ++j) acc[j] = fmaf(xvk, wk[j], acc[j]);
                }
            }
        }
    }
    // cross-wave reduce: smem reused as red[128][GK_STRIDE], wave g writes cols g*16..+15
    __syncthreads();
    {
        float* red = smem + crow * GK_STRIDE + g * 16;
#pragma unroll
        for (int j = 0; j < 16; j += 4) {
            f32x4 v; v.x = acc[j]; v.y = acc[j + 1]; v.z = acc[j + 2]; v.w = acc[j + 3];
            *reinterpret_cast<f32x4*>(red + j) = v;
        }
    }
    __syncthreads();
    // final: thread (row = t>>2, q = t&3) sums the 4 slices, scales, packs fp16
    {
        int fr = t >> 2, q = t & 3;
        int v = row0 + fr;
        if (v < N_NODES) {
            const float* rb = smem + fr * GK_STRIDE + q * 4;
            f32x4 s0 = *reinterpret_cast<const f32x4*>(rb);
            f32x4 s1 = *reinterpret_cast<const f32x4*>(rb + 16);
            f32x4 s2 = *reinterpret_cast<const f32x4*>(rb + 32);
            f32x4 s3 = *reinterpret_cast<const f32x4*>(rb + 48);
            float dv = dinv[v];
            float r0 = dv * (s0.x + s1.x + s2.x + s3.x);
            float r1 = dv * (s0.y + s1.y + s2.y + s3.y);
            float r2 = dv * (s0.z + s1.z + s2.z + s3.z);
            float r3 = dv * (s0.w + s1.w + s2.w + s3.w);
            u32x2 o; o.x = f2h(r0, r1); o.y = f2h(r2, r3);
            ntstore(reinterpret_cast<u32x2*>(h1h + (size_t)v * 8 + q * 2), o);
        }
    }
}

// ---------------- AGG1 + fused GEMM2: CSR pull, 4 lanes per dst ----------------
// Each 4-lane group owns one dst row: lane q gathers+sums quarter q (4 floats)
// of the 16-feature h1 rows, applies dinv/bias/relu, then the group computes
// the 16x3 GEMM against W2 via in-register partials + 2 shfl_xor reduces.
__global__ __launch_bounds__(512) void k_agg1(const unsigned int* __restrict__ pairs,
                                              const int* __restrict__ rows,
                                              const float* __restrict__ dinv,
                                              const unsigned int* __restrict__ h1h,
                                              const float* __restrict__ b1,
                                              const float* __restrict__ W2,
                                              unsigned int* __restrict__ h2h) {
    int b = blockIdx.x, t = threadIdx.x;
    int q = t & 3;            // quarter of the 16-feature row (4 floats)
    int l = t >> 2;           // local dst 0..127
    int v = b * 128 + l;
    if (v >= N_NODES) return;
    int e = rows[b * 128 + l];
    int st = b * CAP + (e >> 16);
    int cnt = e & 0xffff;
    int qo = q * 2;           // uint offset into the 8-uint h1 row
    float dv = dinv[v];
    float s0 = 0.f, s1 = 0.f, s2 = 0.f, s3 = 0.f;
    int i = 0;
    for (; i + 8 <= cnt; i += 8) {
        unsigned p[8];
#pragma unroll
        for (int u = 0; u < 8; ++u) p[u] = ntload(pairs + st + i + u);
        u32x2 A[8];
#pragma unroll
        for (int u = 0; u < 8; ++u)
            A[u] = *reinterpret_cast<const u32x2*>(h1h + (size_t)(p[u] >> 7) * 8 + qo);
#pragma unroll
        for (int u = 0; u < 8; ++u) {
            float2 f0 = h2f(A[u].x), f1 = h2f(A[u].y);
            s0 += f0.x; s1 += f0.y; s2 += f1.x; s3 += f1.y;
        }
    }
    for (; i < cnt; ++i) {
        unsigned p = ntload(pairs + st + i);
        u32x2 A = *reinterpret_cast<const u32x2*>(h1h + (size_t)(p >> 7) * 8 + qo);
        float2 f0 = h2f(A.x), f1 = h2f(A.y);
        s0 += f0.x; s1 += f0.y; s2 += f1.x; s3 += f1.y;
    }
    // self loop (h1h already dinv[v]-scaled) + bias + relu -> a1 quarter in regs
    u32x2 S = *reinterpret_cast<const u32x2*>(h1h + (size_t)v * 8 + qo);
    float2 t0 = h2f(S.x), t1 = h2f(S.y);
    f32x4 bb = reinterpret_cast<const f32x4*>(b1)[q];
    float a0 = fmaxf(fmaf(dv, s0 + t0.x, bb.x), 0.f);
    float a1 = fmaxf(fmaf(dv, s1 + t0.y, bb.y), 0.f);
    float a2 = fmaxf(fmaf(dv, s2 + t1.x, bb.z), 0.f);
    float a3 = fmaxf(fmaf(dv, s3 + t1.y, bb.w), 0.f);
    // fused GEMM2: partial (4 of 16 k-terms) of a1row @ W2 [16x3]
    const float* Wq = W2 + q * 4 * 3;
    float c0 = fmaf(a0, Wq[0], fmaf(a1, Wq[3], fmaf(a2, Wq[6],  a3 * Wq[9])));
    float c1 = fmaf(a0, Wq[1], fmaf(a1, Wq[4], fmaf(a2, Wq[7],  a3 * Wq[10])));
    float c2 = fmaf(a0, Wq[2], fmaf(a1, Wq[5], fmaf(a2, Wq[8],  a3 * Wq[11])));
    // reduce across the 4-lane group (lanes l*4 .. l*4+3 are wave-contiguous)
    c0 += __shfl_xor(c0, 1); c0 += __shfl_xor(c0, 2);
    c1 += __shfl_xor(c1, 1); c1 += __shfl_xor(c1, 2);
    c2 += __shfl_xor(c2, 1); c2 += __shfl_xor(c2, 2);
    if (q == 0) {
        u32x2 o;
        o.x = f2h(dv * c0, dv * c1);
        o.y = f2h(dv * c2, 0.f);
        ntstore(reinterpret_cast<u32x2*>(h2h) + v, o);
    }
}

// ---------------- AGG2: CSR pull, 2 lanes per dst + bias + log_softmax ----------------
__global__ __launch_bounds__(256) void k_agg2(const unsigned int* __restrict__ pairs,
                                              const int* __restrict__ rows,
                                              const float* __restrict__ dinv,
                                              const unsigned int* __restrict__ h2h,
                                              const float* __restrict__ b2,
                                              float* __restrict__ out) {
    int b = blockIdx.x, t = threadIdx.x;
    int half = t & 1;         // stride-2 split of the run
    int l = t >> 1;           // local dst 0..127
    int v = b * 128 + l;
    if (v >= N_NODES) return; // both lanes of a pair exit together
    int e = rows[b * 128 + l];
    int st = b * CAP + (e >> 16);
    int cnt = e & 0xffff;
    const u32x2* h2v = reinterpret_cast<const u32x2*>(h2h);
    float c0 = 0.f, c1 = 0.f, c2 = 0.f;
    int i = half;
    for (; i + 6 < cnt; i += 8) {
        unsigned p0 = ntload(pairs + st + i);
        unsigned p1 = ntload(pairs + st + i + 2);
        unsigned p2 = ntload(pairs + st + i + 4);
        unsigned p3 = ntload(pairs + st + i + 6);
        u32x2 A = h2v[p0 >> 7];
        u32x2 B = h2v[p1 >> 7];
        u32x2 C = h2v[p2 >> 7];
        u32x2 D = h2v[p3 >> 7];
        float2 f01, f2_;
        f01 = h2f(A.x); f2_ = h2f(A.y); c0 += f01.x; c1 += f01.y; c2 += f2_.x;
        f01 = h2f(B.x); f2_ = h2f(B.y); c0 += f01.x; c1 += f01.y; c2 += f2_.x;
        f01 = h2f(C.x); f2_ = h2f(C.y); c0 += f01.x; c1 += f01.y; c2 += f2_.x;
        f01 = h2f(D.x); f2_ = h2f(D.y); c0 += f01.x; c1 += f01.y; c2 += f2_.x;
    }
    for (; i < cnt; i += 2) {
        unsigned p = ntload(pairs + st + i);
        u32x2 A = h2v[p >> 7];
        float2 f01 = h2f(A.x), f2_ = h2f(A.y);
        c0 += f01.x; c1 += f01.y; c2 += f2_.x;
    }
    // combine the stride-2 partials
    c0 += __shfl_xor(c0, 1);
    c1 += __shfl_xor(c1, 1);
    c2 += __shfl_xor(c2, 1);
    if (half == 0) {
        float dv = dinv[v];
        u32x2 hv = h2v[v];                       // self loop (already dv*h2)
        float2 f01 = h2f(hv.x), f2_ = h2f(hv.y);
        float z0 = fmaf(dv, c0 + f01.x, b2[0]);
        float z1 = fmaf(dv, c1 + f01.y, b2[1]);
        float z2 = fmaf(dv, c2 + f2_.x, b2[2]);
        float mx = fmaxf(z0, fmaxf(z1, z2));
        float lse = logf(expf(z0 - mx) + expf(z1 - mx) + expf(z2 - mx));
        out[v * 3 + 0] = z0 - mx - lse;
        out[v * 3 + 1] = z1 - mx - lse;
        out[v * 3 + 2] = z2 - mx - lse;
    }
}

extern "C" void kernel_launch(void* const* d_in, const int* in_sizes, int n_in,
                              void* d_out, int out_size, void* d_ws, size_t ws_size,
                              hipStream_t stream) {
    (void)in_sizes; (void)n_in; (void)out_size; (void)ws_size;
    const float* x  = (const float*)d_in[0];
    const float* W1 = (const float*)d_in[1];
    const float* b1 = (const float*)d_in[2];
    const float* W2 = (const float*)d_in[3];
    const float* b2 = (const float*)d_in[4];
    const int*   ei = (const int*)d_in[5];
    const int* src = ei;
    const int* dst = ei + N_EDGES;
    float* out = (float*)d_out;

    int* ws = (int*)d_ws;
    int*          gcur  = ws + OFF_GCUR;
    float*        dinv  = (float*)(ws + OFF_DINV);
    unsigned int* pairs = (unsigned int*)(ws + OFF_PAIRS);
    int*          rows  = ws + OFF_ROWS;
    unsigned int* h1h   = (unsigned int*)(ws + OFF_H1H);
    unsigned int* h2h   = (unsigned int*)(ws + OFF_H2H);

    k_init <<<(NB + 255) / 256, 256, 0, stream>>>(gcur);
    k_part <<<NBLK_PART, 512, 0, stream>>>(src, dst, gcur, pairs);
    k_sort <<<NB, 512, 0, stream>>>(pairs, gcur, dinv, rows);
    k_gemm1<<<NB, 512, 0, stream>>>(x, W1, dinv, h1h);
    k_agg1 <<<NB, 512, 0, stream>>>(pairs, rows, dinv, h1h, b1, W2, h2h);
    k_agg2 <<<NB, 256, 0, stream>>>(pairs, rows, dinv, h2h, b2, out);
}